// Round 5
// baseline (322.269 us; speedup 1.0000x reference)
//
#include <hip/hip_runtime.h>
#include <math.h>

#define DIM 32
#define BLK 256
#define JSPLIT 16   // j-chunks -> grid.y ; 16 fp64-atomic writers per out row
#define ITPB 8      // i-tiles per block (8*16 = 128 rows), 4 waves x RI
#define RI   2      // i-tiles per wave
#define GTT  16     // j-tiles between fp32->fp64 flushes (256 j)

typedef _Float16 half8 __attribute__((ext_vector_type(8)));
typedef float    f32x4 __attribute__((ext_vector_type(4)));
typedef float    f32x2 __attribute__((ext_vector_type(2)));

struct hl16 { half8 h; half8 l; };   // 32 B fragment record (hi + lo plane)

// out[i] = 2^(c2*||x_i||^2) * sum_j 2^(bf_j + <mf*x_i, y_j>)
//   c2 = -ls*log2(e) (fp64, exact per-i factor in epilogue)
//   bf_j = fp32(c2*||y_j||^2) -> MFMA C-init splat
//   f16 hi/lo split (lo plane *2^12 to stay f16-normal):
//     cm = Ah*Bh + bf ; cl = Ah*Bl + Al*Bh ; f = cm + cl*2^-12
//   exp2 fp32; fp32 partials flushed to fp64 every GTT tiles; fp64 atomics.
// This rev: scalar-pipe addressing (uniform tile base + lane index),
//   interleaved h/l records, packed v_pk_fma/add_f32 epilogue, hoisted zero C.

__global__ __launch_bounds__(BLK) void rbf_prep(
    const float* __restrict__ lsp, const float* __restrict__ x,
    const float* __restrict__ y, int n, int m,
    double* __restrict__ acc, double* __restrict__ scale,
    float* __restrict__ bf, hl16* __restrict__ xhl, hl16* __restrict__ yhl)
{
    int i = blockIdx.x * BLK + threadIdx.x;
    const double c2 = -(double)lsp[0] * 1.4426950408889634074; // -ls*log2(e)
    const float mf = (float)(-2.0 * c2);
    if (i < n) {
        const float* xp = x + (size_t)i * DIM;
        double xs = 0.0;
        #pragma unroll
        for (int d = 0; d < DIM; ++d) { double v = (double)xp[d]; xs = fma(v, v, xs); }
        acc[i] = 0.0;
        scale[i] = exp2(c2 * xs);
        const int it = i >> 4, r15 = i & 15;
        #pragma unroll
        for (int q = 0; q < 4; ++q) {
            half8 hh, hl;
            #pragma unroll
            for (int d = 0; d < 8; ++d) {
                float v = xp[q * 8 + d] * mf;
                _Float16 h = (_Float16)v;
                hh[d] = h;
                hl[d] = (_Float16)((v - (float)h) * 4096.0f);
            }
            xhl[it * 64 + q * 16 + r15].h = hh;
            xhl[it * 64 + q * 16 + r15].l = hl;
        }
    }
    if (i < m) {
        const float* yp = y + (size_t)i * DIM;
        double ys = 0.0;
        #pragma unroll
        for (int d = 0; d < DIM; ++d) { double v = (double)yp[d]; ys = fma(v, v, ys); }
        bf[i] = (float)(c2 * ys);
        const int it = i >> 4, r15 = i & 15;
        #pragma unroll
        for (int q = 0; q < 4; ++q) {
            half8 hh, hl;
            #pragma unroll
            for (int d = 0; d < 8; ++d) {
                float v = yp[q * 8 + d];
                _Float16 h = (_Float16)v;
                hh[d] = h;
                hl[d] = (_Float16)((v - (float)h) * 4096.0f);
            }
            yhl[it * 64 + q * 16 + r15].h = hh;
            yhl[it * 64 + q * 16 + r15].l = hl;
        }
    }
}

__global__ __launch_bounds__(BLK, 4) void rbf_main(
    const hl16* __restrict__ xhl, const hl16* __restrict__ yhl,
    const float* __restrict__ bf, double* __restrict__ acc, int chunk_j)
{
    const int lane = threadIdx.x & 63;
    const int wave = threadIdx.x >> 6;
    const int itbase = blockIdx.x * ITPB + wave * RI;
    const int c15 = lane & 15;

    half8 ah[RI], al[RI];
    #pragma unroll
    for (int r = 0; r < RI; ++r) {
        ah[r] = xhl[(itbase + r) * 64 + lane].h;
        al[r] = xhl[(itbase + r) * 64 + lane].l;
    }

    const int jt0 = (blockIdx.y * chunk_j) >> 4;
    const int njt = chunk_j >> 4;                 // 128 j-tiles per chunk

    const f32x4 zq = {0.0f, 0.0f, 0.0f, 0.0f};    // hoisted zero C
    const float k12 = 0x1p-12f;

    double accd[RI][4];
    #pragma unroll
    for (int r = 0; r < RI; ++r)
        #pragma unroll
        for (int e = 0; e < 4; ++e) accd[r][e] = 0.0;

    // 1-deep pipeline on B fragments; all tile addressing is wave-uniform
    half8 bh = yhl[(size_t)jt0 * 64 + lane].h;
    half8 bl = yhl[(size_t)jt0 * 64 + lane].l;
    float bfv = bf[jt0 * 16 + c15];

    for (int g = 0; g < njt / GTT; ++g) {
        f32x2 accf[RI][2];
        #pragma unroll
        for (int r = 0; r < RI; ++r) {
            accf[r][0] = (f32x2){0.0f, 0.0f};
            accf[r][1] = (f32x2){0.0f, 0.0f};
        }

        #pragma unroll
        for (int tt = 0; tt < GTT; ++tt) {
            const int jt = jt0 + g * GTT + tt;
            int jn = jt + 1; if (jn >= jt0 + njt) jn = jt0;   // scalar cselect
            const hl16* __restrict__ yt = yhl + (size_t)jn * 64; // uniform base
            half8 bh_n = yt[lane].h;
            half8 bl_n = yt[lane].l;
            float bf_n = (bf + jn * 16)[c15];

            const f32x4 cbf = {bfv, bfv, bfv, bfv};   // shared across r
            #pragma unroll
            for (int r = 0; r < RI; ++r) {
                f32x4 cm = __builtin_amdgcn_mfma_f32_16x16x32_f16(ah[r], bh, cbf, 0, 0, 0);
                f32x4 cl = __builtin_amdgcn_mfma_f32_16x16x32_f16(ah[r], bl, zq, 0, 0, 0);
                cl = __builtin_amdgcn_mfma_f32_16x16x32_f16(al[r], bh, cl, 0, 0, 0);
                f32x2 f0 = {cm[0], cm[1]}, f1 = {cm[2], cm[3]};
                f32x2 l0 = {cl[0], cl[1]}, l1 = {cl[2], cl[3]};
                f0 = l0 * k12 + f0;                   // v_pk_fma_f32
                f1 = l1 * k12 + f1;
                f32x2 e0 = {__builtin_amdgcn_exp2f(f0.x), __builtin_amdgcn_exp2f(f0.y)};
                f32x2 e1 = {__builtin_amdgcn_exp2f(f1.x), __builtin_amdgcn_exp2f(f1.y)};
                accf[r][0] += e0;                     // v_pk_add_f32
                accf[r][1] += e1;
            }
            bh = bh_n; bl = bl_n; bfv = bf_n;
        }
        #pragma unroll
        for (int r = 0; r < RI; ++r) {
            accd[r][0] += (double)accf[r][0].x;
            accd[r][1] += (double)accf[r][0].y;
            accd[r][2] += (double)accf[r][1].x;
            accd[r][3] += (double)accf[r][1].y;
        }
    }

    // sum the 16 j-columns: fp64 butterfly across the 16-lane col groups
    #pragma unroll
    for (int r = 0; r < RI; ++r) {
        #pragma unroll
        for (int e = 0; e < 4; ++e) {
            double v = accd[r][e];
            v += __shfl_xor(v, 1, 64);
            v += __shfl_xor(v, 2, 64);
            v += __shfl_xor(v, 4, 64);
            v += __shfl_xor(v, 8, 64);
            if (c15 == 0) {
                int row = (itbase + r) * 16 + (lane >> 4) * 4 + e;
                atomicAdd(&acc[row], v);   // fp64, JSPLIT writers per row
            }
        }
    }
}

__global__ __launch_bounds__(BLK) void rbf_finish(
    const double* __restrict__ acc, const double* __restrict__ scale,
    float* __restrict__ out, int n)
{
    int i = blockIdx.x * BLK + threadIdx.x;
    if (i < n) out[i] = (float)(acc[i] * scale[i]);
}

extern "C" void kernel_launch(void* const* d_in, const int* in_sizes, int n_in,
                              void* d_out, int out_size, void* d_ws, size_t ws_size,
                              hipStream_t stream)
{
    const float* ls = (const float*)d_in[0];
    const float* x  = (const float*)d_in[1];
    const float* y  = (const float*)d_in[2];
    const int n = in_sizes[1] / DIM;   // 32768
    const int m = in_sizes[2] / DIM;   // 32768
    float* out = (float*)d_out;

    // ws: acc[n] f64 | scale[n] f64 | bf[m] f32 | xhl (n/16*64 hl16) | yhl
    // total ~8.6 MB
    char* ws = (char*)d_ws;
    double* acc   = (double*)ws;
    double* scale = acc + n;
    float*  bf    = (float*)(scale + n);
    hl16*   xhl   = (hl16*)(bf + m);
    hl16*   yhl   = xhl + (size_t)(n / 16) * 64;

    const int nm = (n > m) ? n : m;
    rbf_prep<<<(nm + BLK - 1) / BLK, BLK, 0, stream>>>(
        ls, x, y, n, m, acc, scale, bf, xhl, yhl);

    const int chunk = m / JSPLIT;                 // 2048
    dim3 grid(n / (16 * ITPB), JSPLIT);           // 256 x 16
    rbf_main<<<grid, BLK, 0, stream>>>(xhl, yhl, bf, acc, chunk);

    rbf_finish<<<(n + BLK - 1) / BLK, BLK, 0, stream>>>(acc, scale, out, n);
}

// Round 6
// 303.367 us; speedup vs baseline: 1.0623x; 1.0623x over previous
//
#include <hip/hip_runtime.h>
#include <math.h>

#define DIM 32
#define BLK 256
#define JSPLIT 16   // j-chunks -> grid.y ; 16 fp64-atomic writers per out row
#define RI   4      // i-tiles per wave (64 rows) -> 1024 pairs per wave-jtile
#define ITPB (4*RI) // i-tiles per block (16 tiles = 256 rows)
#define GTT  16     // j-tiles between fp32->fp64 flushes (256 j)

typedef _Float16 half8 __attribute__((ext_vector_type(8)));
typedef float    f32x4 __attribute__((ext_vector_type(4)));
typedef float    f32x2 __attribute__((ext_vector_type(2)));

struct hl16 { half8 h; half8 l; };   // 32 B fragment record (hi + lo plane)

// out[i] = 2^(c2*||x_i||^2) * sum_j 2^(bf_j + <mf*x_i, y_j>)
//   c2 = -ls*log2(e) (fp64, exact per-i factor in epilogue)
//   f16 hi/lo split (lo plane *2^12 to stay f16-normal):
//     cm = Ah*Bh ; cl = Ah*Bl + Al*Bh ; f = (cm + cl*2^-12) + bf_j
//   exp2 fp32; fp32 partials flushed to fp64 every GTT tiles; fp64 atomics.
// R5: RI=4 (2x pairs per B-load), parity double-buffered B sets (no rotation
//   movs), persistent zero-C quad for both MFMAs (C!=D operand, no splat),
//   bf_j folded with one packed add after the MFMAs.

__global__ __launch_bounds__(BLK) void rbf_prep(
    const float* __restrict__ lsp, const float* __restrict__ x,
    const float* __restrict__ y, int n, int m,
    double* __restrict__ acc, double* __restrict__ scale,
    float* __restrict__ bf, hl16* __restrict__ xhl, hl16* __restrict__ yhl)
{
    int i = blockIdx.x * BLK + threadIdx.x;
    const double c2 = -(double)lsp[0] * 1.4426950408889634074; // -ls*log2(e)
    const float mf = (float)(-2.0 * c2);
    if (i < n) {
        const float* xp = x + (size_t)i * DIM;
        double xs = 0.0;
        #pragma unroll
        for (int d = 0; d < DIM; ++d) { double v = (double)xp[d]; xs = fma(v, v, xs); }
        acc[i] = 0.0;
        scale[i] = exp2(c2 * xs);
        const int it = i >> 4, r15 = i & 15;
        #pragma unroll
        for (int q = 0; q < 4; ++q) {
            half8 hh, hl;
            #pragma unroll
            for (int d = 0; d < 8; ++d) {
                float v = xp[q * 8 + d] * mf;
                _Float16 h = (_Float16)v;
                hh[d] = h;
                hl[d] = (_Float16)((v - (float)h) * 4096.0f);
            }
            xhl[it * 64 + q * 16 + r15].h = hh;
            xhl[it * 64 + q * 16 + r15].l = hl;
        }
    }
    if (i < m) {
        const float* yp = y + (size_t)i * DIM;
        double ys = 0.0;
        #pragma unroll
        for (int d = 0; d < DIM; ++d) { double v = (double)yp[d]; ys = fma(v, v, ys); }
        bf[i] = (float)(c2 * ys);
        const int it = i >> 4, r15 = i & 15;
        #pragma unroll
        for (int q = 0; q < 4; ++q) {
            half8 hh, hl;
            #pragma unroll
            for (int d = 0; d < 8; ++d) {
                float v = yp[q * 8 + d];
                _Float16 h = (_Float16)v;
                hh[d] = h;
                hl[d] = (_Float16)((v - (float)h) * 4096.0f);
            }
            yhl[it * 64 + q * 16 + r15].h = hh;
            yhl[it * 64 + q * 16 + r15].l = hl;
        }
    }
}

__global__ __launch_bounds__(BLK, 4) void rbf_main(
    const hl16* __restrict__ xhl, const hl16* __restrict__ yhl,
    const float* __restrict__ bf, double* __restrict__ acc, int chunk_j)
{
    const int lane = threadIdx.x & 63;
    const int wave = threadIdx.x >> 6;
    const int itbase = blockIdx.x * ITPB + wave * RI;
    const int c15 = lane & 15;

    half8 ah[RI], al[RI];
    #pragma unroll
    for (int r = 0; r < RI; ++r) {
        ah[r] = xhl[(itbase + r) * 64 + lane].h;
        al[r] = xhl[(itbase + r) * 64 + lane].l;
    }

    const int jt0 = (blockIdx.y * chunk_j) >> 4;
    const int njt = chunk_j >> 4;                 // 128 j-tiles per chunk

    const f32x4 zq = {0.0f, 0.0f, 0.0f, 0.0f};    // persistent zero C quad
    const float k12 = 0x1p-12f;

    double accd[RI][4];
    #pragma unroll
    for (int r = 0; r < RI; ++r)
        #pragma unroll
        for (int e = 0; e < 4; ++e) accd[r][e] = 0.0;

    // parity double-buffered B fragments; tile addressing is wave-uniform
    half8 bh[2], bl[2];
    float bfv[2];
    bh[0] = yhl[(size_t)jt0 * 64 + lane].h;
    bl[0] = yhl[(size_t)jt0 * 64 + lane].l;
    bfv[0] = bf[jt0 * 16 + c15];

    for (int g = 0; g < njt / GTT; ++g) {
        f32x2 accf[RI][2];
        #pragma unroll
        for (int r = 0; r < RI; ++r) {
            accf[r][0] = (f32x2){0.0f, 0.0f};
            accf[r][1] = (f32x2){0.0f, 0.0f};
        }

        #pragma unroll
        for (int tt = 0; tt < GTT; ++tt) {
            const int cur = tt & 1, nxt = cur ^ 1;
            const int jt = jt0 + g * GTT + tt;
            int jn = jt + 1; if (jn >= jt0 + njt) jn = jt0;   // scalar cselect
            const hl16* __restrict__ yt = yhl + (size_t)jn * 64;
            bh[nxt] = yt[lane].h;
            bl[nxt] = yt[lane].l;
            bfv[nxt] = (bf + jn * 16)[c15];

            f32x2 bf2 = {bfv[cur], bfv[cur]};
            #pragma unroll
            for (int r = 0; r < RI; ++r) {
                f32x4 cm = __builtin_amdgcn_mfma_f32_16x16x32_f16(ah[r], bh[cur], zq, 0, 0, 0);
                f32x4 cl = __builtin_amdgcn_mfma_f32_16x16x32_f16(ah[r], bl[cur], zq, 0, 0, 0);
                cl = __builtin_amdgcn_mfma_f32_16x16x32_f16(al[r], bh[cur], cl, 0, 0, 0);
                f32x2 f0 = {cm[0], cm[1]}, f1 = {cm[2], cm[3]};
                f32x2 l0 = {cl[0], cl[1]}, l1 = {cl[2], cl[3]};
                f0 = l0 * k12 + f0;                   // v_pk_fma_f32
                f1 = l1 * k12 + f1;
                f0 = f0 + bf2;                        // fold bf_j (v_pk_add_f32)
                f1 = f1 + bf2;
                f32x2 e0 = {__builtin_amdgcn_exp2f(f0.x), __builtin_amdgcn_exp2f(f0.y)};
                f32x2 e1 = {__builtin_amdgcn_exp2f(f1.x), __builtin_amdgcn_exp2f(f1.y)};
                accf[r][0] += e0;
                accf[r][1] += e1;
            }
        }
        #pragma unroll
        for (int r = 0; r < RI; ++r) {
            accd[r][0] += (double)accf[r][0].x;
            accd[r][1] += (double)accf[r][0].y;
            accd[r][2] += (double)accf[r][1].x;
            accd[r][3] += (double)accf[r][1].y;
        }
    }

    // sum the 16 j-columns: fp64 butterfly across the 16-lane col groups
    #pragma unroll
    for (int r = 0; r < RI; ++r) {
        #pragma unroll
        for (int e = 0; e < 4; ++e) {
            double v = accd[r][e];
            v += __shfl_xor(v, 1, 64);
            v += __shfl_xor(v, 2, 64);
            v += __shfl_xor(v, 4, 64);
            v += __shfl_xor(v, 8, 64);
            if (c15 == 0) {
                int row = (itbase + r) * 16 + (lane >> 4) * 4 + e;
                atomicAdd(&acc[row], v);   // fp64, JSPLIT writers per row
            }
        }
    }
}

__global__ __launch_bounds__(BLK) void rbf_finish(
    const double* __restrict__ acc, const double* __restrict__ scale,
    float* __restrict__ out, int n)
{
    int i = blockIdx.x * BLK + threadIdx.x;
    if (i < n) out[i] = (float)(acc[i] * scale[i]);
}

extern "C" void kernel_launch(void* const* d_in, const int* in_sizes, int n_in,
                              void* d_out, int out_size, void* d_ws, size_t ws_size,
                              hipStream_t stream)
{
    const float* ls = (const float*)d_in[0];
    const float* x  = (const float*)d_in[1];
    const float* y  = (const float*)d_in[2];
    const int n = in_sizes[1] / DIM;   // 32768
    const int m = in_sizes[2] / DIM;   // 32768
    float* out = (float*)d_out;

    // ws: acc[n] f64 | scale[n] f64 | bf[m] f32 | xhl (n/16*64 hl16) | yhl
    // total ~8.6 MB
    char* ws = (char*)d_ws;
    double* acc   = (double*)ws;
    double* scale = acc + n;
    float*  bf    = (float*)(scale + n);
    hl16*   xhl   = (hl16*)(bf + m);
    hl16*   yhl   = xhl + (size_t)(n / 16) * 64;

    const int nm = (n > m) ? n : m;
    rbf_prep<<<(nm + BLK - 1) / BLK, BLK, 0, stream>>>(
        ls, x, y, n, m, acc, scale, bf, xhl, yhl);

    const int chunk = m / JSPLIT;                 // 2048
    dim3 grid(n / (16 * ITPB), JSPLIT);           // 128 x 16
    rbf_main<<<grid, BLK, 0, stream>>>(xhl, yhl, bf, acc, chunk);

    rbf_finish<<<(n + BLK - 1) / BLK, BLK, 0, stream>>>(acc, scale, out, n);
}